// Round 8
// baseline (1925.428 us; speedup 1.0000x reference)
//
#include <hip/hip_runtime.h>
#include <hip/hip_bf16.h>

typedef unsigned short u16;
typedef unsigned int u32;
typedef __attribute__((ext_vector_type(8))) short short8;
typedef __attribute__((ext_vector_type(8))) unsigned short u16x8;
typedef __attribute__((ext_vector_type(4))) unsigned short u16x4;
typedef __attribute__((ext_vector_type(4))) float f32x4;

#define BN_EPS 1e-5f
#define PADW 66
#define CATC 2560

__device__ __forceinline__ u16 f2b(float f) {
    __hip_bfloat16 h = __float2bfloat16(f);
    return *reinterpret_cast<u16*>(&h);
}
__device__ __forceinline__ float b2f(u16 u) {
    __hip_bfloat16 h;
    *reinterpret_cast<u16*>(&h) = u;
    return __bfloat162float(h);
}
__device__ __forceinline__ void async_copy16(void* lds, const void* g) {
    __builtin_amdgcn_global_load_lds((const __attribute__((address_space(1))) u32*)g,
                                     (__attribute__((address_space(3))) u32*)lds, 16, 0, 0);
}
__device__ __forceinline__ void fence_() { asm volatile("" ::: "memory"); }
__device__ __forceinline__ void barrier_() { fence_(); __builtin_amdgcn_s_barrier(); fence_(); }

// ===========================================================================
// 256-wide implicit-GEMM conv, B-OPERAND DIRECT-TO-REGISTER (r8).
// r7 post-mortem: kernel was LDS-BW-bound (192 ds_read + 64KB writes/tile =
// ~2800 cyc vs MFMA 1240) -> MfmaUtil ceiling ~55%. Fix: B fragments load
// straight from global (weights, L1/L2-hot) into registers:
//   bb[nj][kk](lane) = B[n0+wc*64+nh*32+nj*16+(lane&15)]
//                       [k0+kk*32+(lane>>4)*8 ..+8]   (16B aligned)
// identical to the old unswizzled LDS fragment. LDS now holds A only
// (2 x 32KB dbuf); per-tile LDS traffic 256KB -> 160KB; ONE barrier/tile
// (B has no LDS hazards; a-frag deps are compiler-counted lgkm).
// Per tile t (buf=t&1):
//   [entry bar] ldBg(B[t]->regs, 8 vm loads) ; ldA a0,a1 (16 ds_read, FIFO)
//   stage A[t+1]->buf^1 (4 gload_lds; skip t==0 (prologued) and tail)
//   q00,q01 (a0) ; q10,q11 (a1)   [compiler: counted vmcnt for B, lgkm for A]
//   vmcnt(0)  (A[t+1] landed; issued ~2000cyc earlier -> free)  [end bar]
// Hazards: stage->buf^1 is safe (t-1's reads of buf^1 drained pre-barrier);
// t's reads of buf safe vs t+1's stage into buf (after t+1's entry bar).
// Registers: frags 96 VGPR + addr ~32 = 128 VGPR + 128 AGPR acc = 256/wave
// = exactly 8 waves/CU. EPI: 0=affine->bf16 padded, 2=affine->f32 NCHW,
// 4=raw f32 split-K partial.
// ===========================================================================
template<int TAPS, int BN, int EPI, int CPT, int NTILES, int KSPLIT>
__global__ __launch_bounds__(512, 2)
void gemm8(const u16* __restrict__ Ag, int cstride,
           const u16* __restrict__ Bg, int ktot_full, int klen,
           const float* __restrict__ alpha, const float* __restrict__ beta,
           u16* __restrict__ outb, int ostride, int ochoff,
           float* __restrict__ outf, int nch)
{
    constexpr int WN   = BN / 4;      // wave n-width (64)
    constexpr int NSUB = WN / 16;     // n-subtiles per wave (4)
    constexpr int NQ   = NSUB / 2;    // n-subtiles per half (2)
    constexpr int ASZ  = 256 * 128;   // bytes per A buffer
    const int KT = klen / 64;

    extern __shared__ __align__(16) char smem[];
    char* smA = smem;                 // 2*ASZ = 64KB

    const int tid  = threadIdx.x;
    const int lane = tid & 63;
    const int wave = tid >> 6;
    const int wr = wave >> 2;         // 0..1
    const int wc = wave & 3;          // 0..3

    const int nwg = gridDim.x;
    const int wg  = blockIdx.x;
    const int swz = (wg & 7) * (nwg >> 3) + (wg >> 3);   // bijective (nwg%8==0)
    const int sel = swz % (NTILES * KSPLIT);
    const int m0  = (swz / (NTILES * KSPLIT)) * 256;
    const int n0  = (sel / KSPLIT) * BN;
    const int ks  = sel % KSPLIT;
    const int kstart = ks * klen;

    // ---- A staging: thread covers chunk sc of rows sr(+64) ----
    const int sr = tid >> 3;
    const int sc = tid & 7;
    const int scx8 = (sc ^ (sr & 7)) * 8;    // swizzled source chunk (u16 off)
    long baseAe[4];
#pragma unroll
    for (int j = 0; j < 4; ++j) {
        int p = m0 + j * 64 + sr;
        int b = p >> 12, h = (p >> 6) & 63, w = p & 63;
        long apix = (TAPS == 1) ? ((long)(b * PADW + h + 1) * PADW + (w + 1))
                                : ((long)(b * PADW + h) * PADW + w);
        baseAe[j] = apix * cstride + scx8;
    }

    auto stA = [&](int bsel, int h, long aoff) {
#pragma unroll
        for (int l = 0; l < 2; ++l) {
            const u16* g = Ag + baseAe[2 * h + l] + aoff;
            async_copy16(smA + bsel * ASZ + h * 16384 + l * 8192 + tid * 16, g);
        }
    };

    // ---- fragment addressing ----
    const int rsel  = lane & 15;
    const int cswz0 = (((lane >> 4)     ^ (lane & 7)) << 4);
    const int cswz1 = (((4 | (lane >> 4)) ^ (lane & 7)) << 4);

    // B direct-global fragment base: row part per-lane, rest wave-uniform.
    const u16* Bbase = Bg + (long)(n0 + wc * 64 + rsel) * ktot_full + ((lane >> 4) * 8);

    f32x4 acc[8][NSUB] = {};
    short8 a0f[4][2], a1f[4][2], bb0[NQ][2], bb1[NQ][2];

    auto ldA = [&](int bsel, int mh, short8 (&aa)[4][2]) {
        const char* base = smA + bsel * ASZ + (wr * 128 + mh * 64 + rsel) * 128;
#pragma unroll
        for (int mi = 0; mi < 4; ++mi) {
            aa[mi][0] = *(const short8*)(base + mi * 2048 + cswz0);
            aa[mi][1] = *(const short8*)(base + mi * 2048 + cswz1);
        }
    };
    auto ldBg = [&](int nh, int k0, short8 (&bb)[NQ][2]) {
#pragma unroll
        for (int nj = 0; nj < NQ; ++nj)
#pragma unroll
            for (int kk = 0; kk < 2; ++kk)
                bb[nj][kk] = *(const short8*)(Bbase + (long)(nh * 32 + nj * 16) * ktot_full
                                              + k0 + kk * 32);
    };
    auto quad = [&](int MH, int NH, short8 (&aa)[4][2], short8 (&bb)[NQ][2]) {
#pragma unroll
        for (int mi = 0; mi < 4; ++mi)
#pragma unroll
            for (int nj = 0; nj < NQ; ++nj)
#pragma unroll
                for (int kk = 0; kk < 2; ++kk)
                    acc[MH * 4 + mi][NH * NQ + nj] =
                        __builtin_amdgcn_mfma_f32_16x16x32_bf16(
                            aa[mi][kk], bb[nj][kk], acc[MH * 4 + mi][NH * NQ + nj], 0, 0, 0);
    };

    // ---- tap-walk state (init mid-walk for split-K) ----
    const int tap0 = kstart / CPT;
    int c0_ = kstart - tap0 * CPT;
    int dx_ = tap0 % 3;
    long aoff_ = ((long)dx_ + (long)(tap0 / 3) * PADW) * cstride + c0_;
    auto adv = [&]() {
        c0_ += 64; aoff_ += 64;
        if (c0_ == CPT) {
            c0_ = 0; aoff_ += (long)cstride - CPT;
            if (++dx_ == 3) { dx_ = 0; aoff_ += (long)(PADW - 3) * cstride; }
        }
    };

    // ---- prologue: A(0) -> buf0, A(1) -> buf1 ----
    stA(0, 0, aoff_); stA(0, 1, aoff_);
    adv();                                 // aoff_ = state(1)
    stA(1, 0, aoff_); stA(1, 1, aoff_);
    // In-loop, aoff_ holds state(kt+1) at each iteration (advanced at end).

    asm volatile("s_waitcnt vmcnt(4)" ::: "memory");   // A(0) landed
    barrier_();

    int kB = kstart;
    for (int kt = 0; kt < KT; ++kt) {
        const int buf = kt & 1;
        // ---- B fragments of tile kt: 8 global 16B loads -> registers
        ldBg(0, kB, bb0); ldBg(1, kB, bb1);
        // ---- A fragment reads, FIFO a0(8) then a1(8)
        ldA(buf, 0, a0f); ldA(buf, 1, a1f);
        // ---- stage A[kt+1] -> buf^1 (kt==0 prologued)
        if (kt >= 1 && kt + 1 < KT) { stA(buf ^ 1, 0, aoff_); stA(buf ^ 1, 1, aoff_); }
        __builtin_amdgcn_s_setprio(1);
        quad(0, 0, a0f, bb0);   // compiler: waits bb0 (counted vmcnt) + a0 (lgkm)
        quad(0, 1, a0f, bb1);
        quad(1, 0, a1f, bb0);   // a1 drained under q00/q01
        quad(1, 1, a1f, bb1);
        __builtin_amdgcn_s_setprio(0);
        // A[kt+1] stage landed (issued ~2000 cyc ago); drains B remnants too.
        asm volatile("s_waitcnt vmcnt(0)" ::: "memory");
        barrier_();
        adv(); kB += 64;
    }

    // ---- epilogue ----
    const int nl = lane & 15, mq = lane >> 4;
#pragma unroll
    for (int s = 0; s < 8; ++s) {
#pragma unroll
        for (int nj = 0; nj < NSUB; ++nj) {
            int n = n0 + wc * WN + nj * 16 + nl;
            float al = (EPI == 4) ? 1.f : alpha[n];
            float be = (EPI == 4) ? 0.f : beta[n];
#pragma unroll
            for (int r = 0; r < 4; ++r) {
                int m = m0 + wr * 128 + s * 16 + mq * 4 + r;
                float v = acc[s][nj][r] * al + be;
                if (EPI == 0) {
                    int b = m >> 12, h = (m >> 6) & 63, w = m & 63;
                    long addr = ((long)(b * PADW + h + 1) * PADW + (w + 1)) * ostride + ochoff + n;
                    outb[addr] = f2b(v);
                } else if (EPI == 2) {
                    int b = m >> 12, h = (m >> 6) & 63, w = m & 63;
                    outf[((long)(b * nch + n) << 12) + (h * 64 + w)] = v;
                } else {
                    outf[(long)ks * ((long)32768 * nch) + (long)m * nch + n] = v;
                }
            }
        }
    }
}

// ------------------- split-K combine: affine(P0+P1) -> bf16 padded -----------
__global__ void combine_k(const float* __restrict__ P,
                          const float* __restrict__ alpha, const float* __restrict__ beta,
                          u16* __restrict__ dst, int dstride, int choff)
{
    int t = threadIdx.x;
    int m = blockIdx.x * 4 + (t >> 6);
    int n = (t & 63) * 4;
    int b = m >> 12, h = (m >> 6) & 63, w = m & 63;
    f32x4 v0 = *(const f32x4*)&P[(long)m * 256 + n];
    f32x4 v1 = *(const f32x4*)&P[(long)32768 * 256 + (long)m * 256 + n];
    f32x4 al = *(const f32x4*)&alpha[n];
    f32x4 be = *(const f32x4*)&beta[n];
    u16x4 r;
#pragma unroll
    for (int i = 0; i < 4; ++i) r[i] = f2b((v0[i] + v1[i]) * al[i] + be[i]);
    *(u16x4*)&dst[((long)(b * PADW + h + 1) * PADW + (w + 1)) * dstride + choff + n] = r;
}

// ------------------- border zero: CAT (2560ch) + F0 (256ch) -----------------
__global__ void border_k(u16* __restrict__ cat, u16* __restrict__ f0)
{
    int i = blockIdx.x;              // 8 * 260
    int b = i / 260, r = i - b * 260;
    int ph, pw;
    if (r < 66)       { ph = 0;        pw = r; }
    else if (r < 132) { ph = 65;       pw = r - 66; }
    else if (r < 196) { ph = r - 131;  pw = 0; }
    else              { ph = r - 195;  pw = 65; }
    long pix = (long)(b * PADW + ph) * PADW + pw;
    int t = threadIdx.x;
    u16x8 z = {};
    *(u16x8*)&cat[pix * CATC + t * 8] = z;
    if (t < 64) *(u16x8*)&cat[pix * CATC + 2048 + t * 8] = z;
    if (t < 32) *(u16x8*)&f0[pix * 256 + t * 8] = z;
}

// ---------------------------------------------------------------------------
// Small implicit-GEMM conv (128x128, BK=32) — used for qkv / squeeze.
// EPI: 1 = affine -> bf16 flat store, 3 = affine+relu -> mean-reduce.
// ---------------------------------------------------------------------------
template<int TAPS, int EPI>
__global__ __launch_bounds__(256, 2)
void gemm_conv(const u16* __restrict__ A, int cstride, int cpt,
               const u16* __restrict__ Bw, int ktot,
               const float* __restrict__ alpha, const float* __restrict__ beta,
               u16* __restrict__ outb, int ostride, int ochoff,
               float* __restrict__ outf, int n_total)
{
    __shared__ u16 As[128][32];
    __shared__ u16 Bs[128][32];
    __shared__ float red[128];

    const int tid  = threadIdx.x;
    const int lane = tid & 63;
    const int wave = tid >> 6;
    const int wr = wave >> 1, wc = wave & 1;
    const int m0 = blockIdx.y * 128;
    const int n0 = blockIdx.x * 128;

    long pixbase[2];
    long browk[2];
#pragma unroll
    for (int i = 0; i < 2; ++i) {
        int row = i * 64 + (tid >> 2);
        int p = m0 + row;
        int b = p >> 12, h = (p >> 6) & 63, w = p & 63;
        if (TAPS == 1) pixbase[i] = (long)(b * PADW + h + 1) * PADW + (w + 1);
        else           pixbase[i] = (long)(b * PADW + h) * PADW + w;
        browk[i] = (long)(n0 + row) * ktot;
    }
    const int chunk = (tid & 3) * 8;

    f32x4 acc[4][4] = {};

    const int steps = ktot / 32;
    int c0 = 0, dx = 0;
    long toff = 0;
    for (int s = 0; s < steps; ++s) {
        const int k0 = s * 32;
#pragma unroll
        for (int i = 0; i < 2; ++i) {
            const u16* ga = A + (pixbase[i] + ((TAPS == 1) ? 0 : toff)) * cstride + c0 + chunk;
            async_copy16((char*)(&As[0][0]) + i * 4096 + tid * 16, ga);
            const u16* gb = Bw + browk[i] + k0 + chunk;
            async_copy16((char*)(&Bs[0][0]) + i * 4096 + tid * 16, gb);
        }
        asm volatile("s_waitcnt vmcnt(0)" ::: "memory");
        __syncthreads();

        short8 af[4], bf[4];
#pragma unroll
        for (int x = 0; x < 4; ++x) {
            af[x] = *(const short8*)&As[wr * 64 + x * 16 + (lane & 15)][(lane >> 4) * 8];
            bf[x] = *(const short8*)&Bs[wc * 64 + x * 16 + (lane & 15)][(lane >> 4) * 8];
        }
#pragma unroll
        for (int mi = 0; mi < 4; ++mi)
#pragma unroll
            for (int ni = 0; ni < 4; ++ni)
                acc[mi][ni] = __builtin_amdgcn_mfma_f32_16x16x32_bf16(af[mi], bf[ni], acc[mi][ni], 0, 0, 0);
        __syncthreads();

        c0 += 32;
        if (TAPS > 1 && c0 == cpt) {
            c0 = 0; dx++; toff += 1;
            if (dx == 3) { dx = 0; toff += PADW - 3; }
        }
    }

    const int nl = lane & 15;
    const int mq = lane >> 4;

    if (EPI == 3) {
        if (tid < 128) red[tid] = 0.f;
        __syncthreads();
#pragma unroll
        for (int ni = 0; ni < 4; ++ni) {
            int ncol = wc * 64 + ni * 16 + nl;
            int n = n0 + ncol;
            float aa = alpha[n], bb = beta[n];
            float ssum = 0.f;
#pragma unroll
            for (int mi = 0; mi < 4; ++mi)
#pragma unroll
                for (int r = 0; r < 4; ++r)
                    ssum += fmaxf(acc[mi][ni][r] * aa + bb, 0.f);
            atomicAdd(&red[ncol], ssum);
        }
        __syncthreads();
        if (tid < 128) {
            int b = m0 >> 12;
            atomicAdd(&outf[b * 256 + n0 + tid], red[tid]);
        }
    } else {
#pragma unroll
        for (int mi = 0; mi < 4; ++mi) {
#pragma unroll
            for (int r = 0; r < 4; ++r) {
                int m = m0 + wr * 64 + mi * 16 + mq * 4 + r;
#pragma unroll
                for (int ni = 0; ni < 4; ++ni) {
                    int n = n0 + wc * 64 + ni * 16 + nl;
                    float v = acc[mi][ni][r] * alpha[n] + beta[n];
                    outb[(long)m * ostride + n] = f2b(v);
                }
            }
        }
    }
}

// ------------------- x: NCHW f32 -> padded NHWC bf16 (vectorized) -----------
__global__ void xpad_k(const float* __restrict__ x, u16* __restrict__ cat)
{
    __shared__ float T[64][68];
    int bh = blockIdx.y;
    int b = bh >> 6, h = bh & 63;
    int c0 = blockIdx.x * 64;
    int t = threadIdx.x;
    const float* xb = x + (((long)b * 2048 + c0) * 64 + h) * 64;
#pragma unroll
    for (int i = 0; i < 4; ++i) {
        int idx = i * 256 + t;          // c*16 + wq
        int c = idx >> 4, wq = (idx & 15) * 4;
        *(f32x4*)&T[c][wq] = *(const f32x4*)&xb[(long)c * 4096 + wq];
    }
    __syncthreads();
    long pbase = ((long)(b * PADW + h + 1) * PADW + 1) * CATC + c0;
#pragma unroll
    for (int j = 0; j < 2; ++j) {
        int idx = j * 256 + t;          // w*8 + cg
        int w = idx >> 3, cg = (idx & 7) * 8;
        u16x8 r;
#pragma unroll
        for (int u = 0; u < 8; ++u) r[u] = f2b(T[cg + u][w]);
        *(u16x8*)&cat[pbase + (long)w * CATC + cg] = r;
    }
}

// ------------------- weight transforms ---------------------------------------
__global__ void prep_w3(const float* __restrict__ w, u16* __restrict__ o, int O, int C)
{
    int idx = blockIdx.x * 256 + threadIdx.x;
    if (idx >= O * C) return;
    int oo = idx / C, c = idx - oo * C;
    const float* s = w + (long)idx * 9;
    long base = (long)oo * 9 * C + c;
#pragma unroll
    for (int t = 0; t < 9; ++t) o[base + (long)t * C] = f2b(s[t]);
}

__global__ void prep_qkv(const float* __restrict__ qw, const float* __restrict__ kw,
                         const float* __restrict__ vw, u16* __restrict__ o)
{
    int idx = blockIdx.x * 256 + threadIdx.x;   // over 384*256
    int n = idx >> 8, c = idx & 255;
    float v;
    if (n < 32) v = qw[n * 256 + c];
    else if (n < 64) v = kw[(n - 32) * 256 + c];
    else if (n < 320) v = vw[(n - 64) * 256 + c];
    else v = 0.f;
    o[idx] = f2b(v);
}

__global__ void prep_cast(const float* __restrict__ w, u16* __restrict__ o, int n)
{
    int i = blockIdx.x * 256 + threadIdx.x;
    if (i < n) o[i] = f2b(w[i]);
}

__global__ void prep_ab(const float* as, const float* ab, const float* am, const float* av,
                        const float* gs, const float* gb, const float* gm, const float* gv, const float* sqb,
                        const float* bs, const float* bb, const float* bm, const float* bv,
                        const float* ts, const float* tb, const float* tm, const float* tv,
                        const float* qb, const float* kb, const float* vb,
                        float* Aa, float* Ba_, float* Ag, float* Bg, float* Ab2, float* Bb2,
                        float* At, float* Bt, float* Aq, float* Bq)
{
    int i = blockIdx.x * 256 + threadIdx.x;
    if (i < 256) { float al = as[i] * rsqrtf(av[i] + BN_EPS); Aa[i] = al; Ba_[i] = ab[i] - am[i] * al; }
    else if (i < 512) { int n = i - 256; float al = gs[n] * rsqrtf(gv[n] + BN_EPS); Ag[n] = al; Bg[n] = gb[n] - gm[n] * al + sqb[n] * al; }
    else if (i < 768) { int n = i - 512; float al = bs[n] * rsqrtf(bv[n] + BN_EPS); Ab2[n] = al; Bb2[n] = bb[n] - bm[n] * al; }
    else if (i < 1280) { int n = i - 768; float al = ts[n] * rsqrtf(tv[n] + BN_EPS); At[n] = al; Bt[n] = tb[n] - tm[n] * al; }
    else if (i < 1664) { int n = i - 1280; Aq[n] = 1.f; Bq[n] = (n < 32) ? qb[n] : (n < 64) ? kb[n - 32] : (n < 320) ? vb[n - 64] : 0.f; }
}

// ------------------- SE: vec -> gate ----------------------------------------
__global__ void gate_k(const float* __restrict__ vacc, const float* __restrict__ fc1w,
                       const float* __restrict__ fc1b, const float* __restrict__ fc2w,
                       const float* __restrict__ fc2b, float* __restrict__ gate)
{
    __shared__ float v[256], hbuf[128];
    int b = blockIdx.x, t = threadIdx.x;
    v[t] = vacc[b * 256 + t] * (1.f / 4096.f);
    __syncthreads();
    if (t < 128) {
        float s = fc1b[t];
        for (int c = 0; c < 256; ++c) s += v[c] * fc1w[t * 256 + c];
        hbuf[t] = fmaxf(s, 0.f);
    }
    __syncthreads();
    float s = fc2b[t];
    for (int j = 0; j < 128; ++j) s += hbuf[j] * fc2w[t * 128 + j];
    gate[b * 256 + t] = 1.f / (1.f + __expf(-s));
}

// ------------------- out_gap -> cat ch 2304..2560 ----------------------------
__global__ void gap_k(const u16* __restrict__ f0, const float* __restrict__ gate, u16* __restrict__ cat)
{
    int p = blockIdx.x, t = threadIdx.x;
    int b = p >> 12, h = (p >> 6) & 63, w = p & 63;
    long ppad = (long)(b * PADW + h + 1) * PADW + (w + 1);
    float f = b2f(f0[ppad * 256 + t]);
    cat[ppad * CATC + 2304 + t] = f2b(f * gate[b * 256 + t]);
}

// ------------------- CCA: Gram (Q.K^T per column AND per row, one launch) ----
__global__ void gram_k(const u16* __restrict__ qkv, float* eH, float* eW)
{
    __shared__ u16 Qs[64][32];
    __shared__ u16 Ks[64][32];
    int g = blockIdx.x;              // 1024 = 2 modes x 512
    int mode = g >> 9;
    int bx = g & 511;
    int b = bx >> 6, s = bx & 63;
    float* e = mode ? eW : eH;
    int tid = threadIdx.x, lane = tid & 63, wave = tid >> 6;
    {
        int r = tid >> 2, ch = (tid & 3) * 8;
        long pix = (mode == 0) ? ((long)(b * 64 + r) * 64 + s) : ((long)(b * 64 + s) * 64 + r);
        const u16* gp = qkv + pix * 384;
        *(u16x8*)&Qs[r][ch] = *(const u16x8*)(gp + ch);
        *(u16x8*)&Ks[r][ch] = *(const u16x8*)(gp + 32 + ch);
    }
    __syncthreads();
    f32x4 acc[4] = {};
    short8 a = *(const short8*)&Qs[wave * 16 + (lane & 15)][(lane >> 4) * 8];
#pragma unroll
    for (int ni = 0; ni < 4; ++ni) {
        short8 bb = *(const short8*)&Ks[ni * 16 + (lane & 15)][(lane >> 4) * 8];
        acc[ni] = __builtin_amdgcn_mfma_f32_16x16x32_bf16(a, bb, acc[ni], 0, 0, 0);
    }
#pragma unroll
    for (int ni = 0; ni < 4; ++ni)
#pragma unroll
        for (int r = 0; r < 4; ++r) {
            int row = wave * 16 + (lane >> 4) * 4 + r;
            int col = ni * 16 + (lane & 15);
            long pix = (mode == 0) ? ((long)(b * 64 + row) * 64 + s) : ((long)(b * 64 + s) * 64 + row);
            e[pix * 64 + col] = acc[ni][r];
        }
}

// ------------------- CCA: joint softmax over [eH | eW] -----------------------
__global__ void softmax_k(const float* __restrict__ eH, const float* __restrict__ eW,
                          u16* __restrict__ aH, u16* __restrict__ aW)
{
    long row = blockIdx.x * 4 + (threadIdx.x >> 6);
    int lane = threadIdx.x & 63;
    float v0 = eH[row * 64 + lane];
    float v1 = eW[row * 64 + lane];
    float m = fmaxf(v0, v1);
#pragma unroll
    for (int off = 32; off; off >>= 1) m = fmaxf(m, __shfl_xor(m, off));
    float e0 = __expf(v0 - m), e1 = __expf(v1 - m);
    float s = e0 + e1;
#pragma unroll
    for (int off = 32; off; off >>= 1) s += __shfl_xor(s, off);
    float inv = 1.f / s;
    aH[row * 64 + lane] = f2b(e0 * inv);
    aW[row * 64 + lane] = f2b(e1 * inv);
}

// ------------------- CCA: oH = aH . V(column) --------------------------------
__global__ __launch_bounds__(256, 2)
void oh_k(const u16* __restrict__ aH, const u16* __restrict__ qkv, float* __restrict__ oHb)
{
    __shared__ float Al[64][68];
    __shared__ u16 Vl[64][264];
    int bx = blockIdx.x;
    int b = bx >> 6, w = bx & 63;
    int t = threadIdx.x;
#pragma unroll
    for (int pass = 0; pass < 2; ++pass) {
        int r = pass * 32 + (t >> 3);
        int ch = (t & 7) * 8;
        u16x8 v = *(const u16x8*)(aH + ((long)(b * 64 + r) * 64 + w) * 64 + ch);
        f32x4 s0, s1;
#pragma unroll
        for (int u = 0; u < 4; ++u) { s0[u] = b2f(v[u]); s1[u] = b2f(v[4 + u]); }
        *(f32x4*)&Al[r][ch] = s0;
        *(f32x4*)&Al[r][ch + 4] = s1;
    }
#pragma unroll
    for (int pass = 0; pass < 8; ++pass) {
        int i = pass * 8 + (t >> 5);
        int ch = (t & 31) * 8;
        *(u16x8*)&Vl[i][ch] = *(const u16x8*)(qkv + ((long)(b * 64 + i) * 64 + w) * 384 + 64 + ch);
    }
    __syncthreads();
    int hb = (t >> 5) * 8, cb = (t & 31) * 8;
    float acc[8][8] = {};
    for (int i = 0; i < 64; ++i) {
        float av[8], vv[8];
        u16x8 v8 = *(const u16x8*)&Vl[i][cb];
#pragma unroll
        for (int u = 0; u < 8; ++u) av[u] = Al[hb + u][i];
#pragma unroll
        for (int u = 0; u < 8; ++u) vv[u] = b2f(v8[u]);
#pragma unroll
        for (int u = 0; u < 8; ++u)
#pragma unroll
            for (int x = 0; x < 8; ++x)
                acc[u][x] += av[u] * vv[x];
    }
#pragma unroll
    for (int u = 0; u < 8; ++u) {
        long base = ((long)(b * 64 + hb + u) * 64 + w) * 256 + cb;
        f32x4 s0, s1;
#pragma unroll
        for (int x = 0; x < 4; ++x) { s0[x] = acc[u][x]; s1[x] = acc[u][4 + x]; }
        *(f32x4*)&oHb[base] = s0;
        *(f32x4*)&oHb[base + 4] = s1;
    }
}

// ------------------- CCA: oW = aW . V(row); combine -> fout ------------------
__global__ __launch_bounds__(256, 2)
void ow_k(const u16* __restrict__ aW, const u16* __restrict__ qkv, const float* __restrict__ oHb,
          const u16* __restrict__ fin, u16* __restrict__ fout, const float* __restrict__ gamma_p)
{
    __shared__ float Al[64][68];
    __shared__ u16 Vl[64][264];
    int bx = blockIdx.x;
    int b = bx >> 6, h = bx & 63;
    int t = threadIdx.x;
    float gamma = gamma_p[0];
#pragma unroll
    for (int pass = 0; pass < 2; ++pass) {
        int r = pass * 32 + (t >> 3);
        int ch = (t & 7) * 8;
        u16x8 v = *(const u16x8*)(aW + ((long)(b * 64 + h) * 64 + r) * 64 + ch);
        f32x4 s0, s1;
#pragma unroll
        for (int u = 0; u < 4; ++u) { s0[u] = b2f(v[u]); s1[u] = b2f(v[4 + u]); }
        *(f32x4*)&Al[r][ch] = s0;
        *(f32x4*)&Al[r][ch + 4] = s1;
    }
#pragma unroll
    for (int pass = 0; pass < 8; ++pass) {
        int j = pass * 8 + (t >> 5);
        int ch = (t & 31) * 8;
        *(u16x8*)&Vl[j][ch] = *(const u16x8*)(qkv + ((long)(b * 64 + h) * 64 + j) * 384 + 64 + ch);
    }
    __syncthreads();
    int wb = (t >> 5) * 8, cb = (t & 31) * 8;
    float acc[8][8] = {};
    for (int j = 0; j < 64; ++j) {
        float av[8], vv[8];
        u16x8 v8 = *(const u16x8*)&Vl[j][cb];
#pragma unroll
        for (int u = 0; u < 8; ++u) av[u] = Al[wb + u][j];
#pragma unroll
        for (int u = 0; u < 8; ++u) vv[u] = b2f(v8[u]);
#pragma unroll
        for (int u = 0; u < 8; ++u)
#pragma unroll
            for (int x = 0; x < 8; ++x)
                acc[u][x] += av[u] * vv[x];
    }
#pragma unroll
    for (int u = 0; u < 8; ++u) {
        int w = wb + u;
        long pix = ((long)(b * 64 + h) * 64 + w) * 256 + cb;
        long pp = ((long)(b * PADW + h + 1) * PADW + (w + 1)) * 256 + cb;
        u16x8 f8 = *(const u16x8*)&fin[pp];
        f32x4 o0 = *(const f32x4*)&oHb[pix];
        f32x4 o1 = *(const f32x4*)&oHb[pix + 4];
        u16x8 r8;
#pragma unroll
        for (int x = 0; x < 8; ++x) {
            float o = acc[u][x] + ((x < 4) ? o0[x] : o1[x - 4]);
            r8[x] = f2b(gamma * o + b2f(f8[x]));
        }
        *(u16x8*)&fout[pp] = r8;
    }
}

// ---------------------------------------------------------------------------
extern "C" void kernel_launch(void* const* d_in, const int* in_sizes, int n_in,
                              void* d_out, int out_size, void* d_ws, size_t ws_size,
                              hipStream_t stream)
{
    const float* x       = (const float*)d_in[0];
    const float* conva_w = (const float*)d_in[2];
    const float* bn_a_s  = (const float*)d_in[3];
    const float* bn_a_b  = (const float*)d_in[4];
    const float* bn_a_m  = (const float*)d_in[5];
    const float* bn_a_v  = (const float*)d_in[6];
    const float* q_w     = (const float*)d_in[7];
    const float* q_b     = (const float*)d_in[8];
    const float* k_w     = (const float*)d_in[9];
    const float* k_b     = (const float*)d_in[10];
    const float* v_w     = (const float*)d_in[11];
    const float* v_b     = (const float*)d_in[12];
    const float* gamma   = (const float*)d_in[13];
    const float* convb_w = (const float*)d_in[14];
    const float* bn_b_s  = (const float*)d_in[15];
    const float* bn_b_b  = (const float*)d_in[16];
    const float* bn_b_m  = (const float*)d_in[17];
    const float* bn_b_v  = (const float*)d_in[18];
    const float* sq_w    = (const float*)d_in[19];
    const float* sq_b    = (const float*)d_in[20];
    const float* bn_g_s  = (const float*)d_in[21];
    const float* bn_g_b  = (const float*)d_in[22];
    const float* bn_g_m  = (const float*)d_in[23];
    const float* bn_g_v  = (const float*)d_in[24];
    const float* fc1_w   = (const float*)d_in[25];
    const float* fc1_b   = (const float*)d_in[26];
    const float* fc2_w   = (const float*)d_in[27];
    const float* fc2_b   = (const float*)d_in[28];
    const float* bott_w  = (const float*)d_in[29];
    const float* bn_t_s  = (const float*)d_in[30];
    const float* bn_t_b  = (const float*)d_in[31];
    const float* bn_t_m  = (const float*)d_in[32];
    const float* bn_t_v  = (const float*)d_in[33];

    char* ws = (char*)d_ws;
    size_t off = 0;
    auto alloc = [&](size_t bytes) { char* p = ws + off; off += (bytes + 255) & ~(size_t)255; return p; };

    u16*   CAT  = (u16*)  alloc((size_t)8 * PADW * PADW * CATC * 2);
    u16*   F0   = (u16*)  alloc((size_t)8 * PADW * PADW * 256 * 2);
    u16*   F1   = (u16*)  alloc((size_t)8 * PADW * PADW * 256 * 2);
    size_t cca_off = off;                 // CCA scratch block — time-shared with P
    u16*   QKV  = (u16*)  alloc((size_t)32768 * 384 * 2);
    float* EH   = (float*)alloc((size_t)32768 * 64 * 4);
    float* EWb  = (float*)alloc((size_t)32768 * 64 * 4);
    u16*   AH   = (u16*)  alloc((size_t)32768 * 64 * 2);
    u16*   AW   = (u16*)  alloc((size_t)32768 * 64 * 2);
    float* OHB  = (float*)alloc((size_t)32768 * 256 * 4);
    float* P    = (float*)(ws + cca_off); // 67.2MB split-K partials (aliases QKV..OHB = 84MB)
    u16*   WA   = (u16*)  alloc((size_t)256 * 18432 * 2);
    u16*   WB   = (u16*)  alloc((size_t)256 * 2304 * 2);
    u16*   WT   = (u16*)  alloc((size_t)512 * 23040 * 2);
    u16*   WQKV = (u16*)  alloc((size_t)384 * 256 * 2);
    u16*   WSQ  = (u16*)  alloc((size_t)256 * 256 * 2);
    float* Aa   = (float*)alloc(256 * 4);
    float* Ba_  = (float*)alloc(256 * 4);
    float* Ag   = (float*)alloc(256 * 4);
    float* Bg   = (float*)alloc(256 * 4);
    float* Ab2  = (float*)alloc(256 * 4);
    float* Bb2  = (float*)alloc(256 * 4);
    float* At   = (float*)alloc(512 * 4);
    float* Bt   = (float*)alloc(512 * 4);
    float* Aq   = (float*)alloc(384 * 4);
    float* Bq   = (float*)alloc(384 * 4);
    float* VACC = (float*)alloc(8 * 256 * 4);
    float* GATE = (float*)alloc(8 * 256 * 4);

    hipFuncSetAttribute((const void*)gemm8<9, 256, 4, 2048, 1, 2>,
                        hipFuncAttributeMaxDynamicSharedMemorySize, 65536);
    hipFuncSetAttribute((const void*)gemm8<9, 256, 4, 256, 1, 2>,
                        hipFuncAttributeMaxDynamicSharedMemorySize, 65536);
    hipFuncSetAttribute((const void*)gemm8<9, 256, 2, 2560, 2, 1>,
                        hipFuncAttributeMaxDynamicSharedMemorySize, 65536);

    hipMemsetAsync(VACC, 0, 8 * 256 * 4, stream);

    border_k<<<8 * 260, 256, 0, stream>>>(CAT, F0);
    prep_w3<<<(256 * 2048 + 255) / 256, 256, 0, stream>>>(conva_w, WA, 256, 2048);
    prep_w3<<<(256 * 256 + 255) / 256, 256, 0, stream>>>(convb_w, WB, 256, 256);
    prep_w3<<<(512 * 2560 + 255) / 256, 256, 0, stream>>>(bott_w, WT, 512, 2560);
    prep_qkv<<<384, 256, 0, stream>>>(q_w, k_w, v_w, WQKV);
    prep_cast<<<256, 256, 0, stream>>>(sq_w, WSQ, 65536);
    prep_ab<<<7, 256, 0, stream>>>(bn_a_s, bn_a_b, bn_a_m, bn_a_v,
                                   bn_g_s, bn_g_b, bn_g_m, bn_g_v, sq_b,
                                   bn_b_s, bn_b_b, bn_b_m, bn_b_v,
                                   bn_t_s, bn_t_b, bn_t_m, bn_t_v,
                                   q_b, k_b, v_b,
                                   Aa, Ba_, Ag, Bg, Ab2, Bb2, At, Bt, Aq, Bq);
    xpad_k<<<dim3(32, 512), 256, 0, stream>>>(x, CAT);

    // conv_a + bn_a -> F0  (B-direct, BN=256, split-K=2 -> f32 partials -> combine)
    gemm8<9, 256, 4, 2048, 1, 2><<<256, 512, 65536, stream>>>(
        CAT, CATC, WA, 18432, 9216, Aa, Ba_, nullptr, 0, 0, P, 256);
    combine_k<<<8192, 256, 0, stream>>>(P, Aa, Ba_, F0, 256, 0);

    // squeeze conv + bn_g + relu + mean -> VACC
    gemm_conv<1, 3><<<dim3(2, 256), 256, 0, stream>>>(F0, 256, 256, WSQ, 256, Ag, Bg, nullptr, 0, 0, VACC, 0);
    gate_k<<<8, 256, 0, stream>>>(VACC, fc1_w, fc1_b, fc2_w, fc2_b, GATE);
    gap_k<<<32768, 256, 0, stream>>>(F0, GATE, CAT);

    // 2 recurrences of criss-cross attention (P region free only after this)
    for (int rec = 0; rec < 2; ++rec) {
        u16* fin = rec ? F1 : F0;
        u16* fout = rec ? F0 : F1;
        gemm_conv<1, 1><<<dim3(3, 256), 256, 0, stream>>>(fin, 256, 256, WQKV, 256, Aq, Bq, QKV, 384, 0, nullptr, 0);
        gram_k<<<1024, 256, 0, stream>>>(QKV, EH, EWb);
        softmax_k<<<8192, 256, 0, stream>>>(EH, EWb, AH, AW);
        oh_k<<<512, 256, 0, stream>>>(AH, QKV, OHB);
        ow_k<<<512, 256, 0, stream>>>(AW, QKV, OHB, fin, fout, gamma);
    }

    // conv_b + bn_b -> CAT channels [2048, 2304)  (B-direct, split-K=2)
    gemm8<9, 256, 4, 256, 1, 2><<<256, 512, 65536, stream>>>(
        F0, 256, WB, 2304, 1152, Ab2, Bb2, nullptr, 0, 0, P, 256);
    combine_k<<<8192, 256, 0, stream>>>(P, Ab2, Bb2, CAT, CATC, 2048);

    // bottleneck conv + bn_t -> d_out  (B-direct, BN=256: 128 x 2 tiles)
    gemm8<9, 256, 2, 2560, 2, 1><<<256, 512, 65536, stream>>>(
        CAT, CATC, WT, 23040, 23040, At, Bt, nullptr, 0, 0, (float*)d_out, 512);
}

// Round 9
// 1166.592 us; speedup vs baseline: 1.6505x; 1.6505x over previous
//
#include <hip/hip_runtime.h>
#include <hip/hip_bf16.h>

typedef unsigned short u16;
typedef unsigned int u32;
typedef __attribute__((ext_vector_type(8))) short short8;
typedef __attribute__((ext_vector_type(8))) unsigned short u16x8;
typedef __attribute__((ext_vector_type(4))) unsigned short u16x4;
typedef __attribute__((ext_vector_type(4))) float f32x4;

#define BN_EPS 1e-5f
#define PADW 66
#define CATC 2560

__device__ __forceinline__ u16 f2b(float f) {
    __hip_bfloat16 h = __float2bfloat16(f);
    return *reinterpret_cast<u16*>(&h);
}
__device__ __forceinline__ float b2f(u16 u) {
    __hip_bfloat16 h;
    *reinterpret_cast<u16*>(&h) = u;
    return __bfloat162float(h);
}
__device__ __forceinline__ void async_copy16(void* lds, const void* g) {
    __builtin_amdgcn_global_load_lds((const __attribute__((address_space(1))) u32*)g,
                                     (__attribute__((address_space(3))) u32*)lds, 16, 0, 0);
}
__device__ __forceinline__ void fence_() { asm volatile("" ::: "memory"); }
__device__ __forceinline__ void barrier_() { fence_(); __builtin_amdgcn_s_barrier(); fence_(); }

// ===========================================================================
// 256-wide implicit-GEMM conv: r7 read-ahead structure + CROSS-TILE B PRE-READ.
// (r8 B-direct-to-register REVERTED: 16-row scatter per load uncoalesced +
//  same-tile consume exposed L2 latency -> 28% MfmaUtil. LDS staging restored.)
// A,B staged in LDS (A dbuf 2x32KB, B dbuf 2x32KB = 128KB). BM=BN=256, BK=64.
// Per K-tile t (buf=t&1), 2 barriers:
//  [entry bar] ldA a0(8); (kt==0: ldB b0,b1(8)); ldA a1(8)   [FIFO]
//              stage A[t+1]->buf^1 (4 gload_lds)
//              q00,q01 (wait a0 via counted lgkm; b already in regs from
//              pre-read at t-1; a1 drains UNDER q00/q01)
//  [mid bar]   stage B[t+2]->buf ; q10,q11
//              vmcnt(4) (retires A[t+1] + B[t+1]; leaves B[t+2])
//              PRE-READ b0,b1[t+1] from buf^1  (B[t+1] landed: after vmcnt;
//              region rewritten only at t+1's mid, after all waves consumed)
//  [end bar]
// Tail: kt+2>=KT -> vmcnt(0). Tile-t+1's q00 then waits only 8 a0 reads
// (~770cyc chip-wide) instead of 12/24 (~1150): B-fragment service moves
// under the previous tile's barrier+MFMA.
// EPI: 0=affine->bf16 padded, 2=affine->f32 NCHW, 4=raw f32 split-K partial.
// ===========================================================================
template<int TAPS, int BN, int EPI, int CPT, int NTILES, int KSPLIT>
__global__ __launch_bounds__(512, 2)
void gemm8(const u16* __restrict__ Ag, int cstride,
           const u16* __restrict__ Bg, int ktot_full, int klen,
           const float* __restrict__ alpha, const float* __restrict__ beta,
           u16* __restrict__ outb, int ostride, int ochoff,
           float* __restrict__ outf, int nch)
{
    constexpr int WN   = BN / 4;      // wave n-width
    constexpr int NSUB = WN / 16;     // n-subtiles per wave
    constexpr int NQ   = NSUB / 2;    // n-subtiles per half
    constexpr int BLH  = BN / 128;    // B gloads per half-tile per thread
    constexpr int ASZ  = 256 * 128;   // bytes per A buffer
    constexpr int BSZ  = BN * 128;    // bytes per B buffer
    const int KT = klen / 64;

    extern __shared__ __align__(16) char smem[];
    char* smA = smem;                 // 2*ASZ
    char* smB = smem + 2 * ASZ;       // 2*BSZ

    const int tid  = threadIdx.x;
    const int lane = tid & 63;
    const int wave = tid >> 6;
    const int wr = wave >> 2;         // 0..1
    const int wc = wave & 3;          // 0..3

    const int nwg = gridDim.x;
    const int wg  = blockIdx.x;
    const int swz = (wg & 7) * (nwg >> 3) + (wg >> 3);   // bijective (nwg%8==0)
    const int sel = swz % (NTILES * KSPLIT);
    const int m0  = (swz / (NTILES * KSPLIT)) * 256;
    const int n0  = (sel / KSPLIT) * BN;
    const int ks  = sel % KSPLIT;
    const int kstart = ks * klen;

    // ---- staging decomposition: thread covers chunk sc of rows sr(+64) ----
    const int sr = tid >> 3;
    const int sc = tid & 7;
    const int scx8 = (sc ^ (sr & 7)) * 8;    // swizzled source chunk (u16 off)
    long baseAe[4];
#pragma unroll
    for (int j = 0; j < 4; ++j) {
        int p = m0 + j * 64 + sr;
        int b = p >> 12, h = (p >> 6) & 63, w = p & 63;
        long apix = (TAPS == 1) ? ((long)(b * PADW + h + 1) * PADW + (w + 1))
                                : ((long)(b * PADW + h) * PADW + w);
        baseAe[j] = apix * cstride + scx8;
    }
    long baseBe[2 * BLH];
#pragma unroll
    for (int h = 0; h < 2; ++h)
#pragma unroll
        for (int l = 0; l < BLH; ++l)
            baseBe[h * BLH + l] = (long)(n0 + h * (BN / 2) + l * 64 + sr) * ktot_full + scx8;

    auto stA = [&](int bsel, int h, long aoff) {
#pragma unroll
        for (int l = 0; l < 2; ++l) {
            const u16* g = Ag + baseAe[2 * h + l] + aoff;
            async_copy16(smA + bsel * ASZ + h * 16384 + l * 8192 + tid * 16, g);
        }
    };
    auto stB = [&](int bsel, int h, int k0) {
#pragma unroll
        for (int l = 0; l < BLH; ++l) {
            const u16* g = Bg + baseBe[h * BLH + l] + k0;
            async_copy16(smB + bsel * BSZ + h * (BSZ / 2) + l * 8192 + tid * 16, g);
        }
    };

    // ---- fragment ds_read addressing (swizzled) ----
    const int rsel  = lane & 15;
    const int cswz0 = (((lane >> 4)     ^ (lane & 7)) << 4);
    const int cswz1 = (((4 | (lane >> 4)) ^ (lane & 7)) << 4);

    f32x4 acc[8][NSUB] = {};
    short8 a0f[4][2], a1f[4][2], b0[NQ][2], b1[NQ][2];

    auto ldA = [&](int bsel, int mh, short8 (&aa)[4][2]) {
        const char* base = smA + bsel * ASZ + (wr * 128 + mh * 64 + rsel) * 128;
#pragma unroll
        for (int mi = 0; mi < 4; ++mi) {
            aa[mi][0] = *(const short8*)(base + mi * 2048 + cswz0);
            aa[mi][1] = *(const short8*)(base + mi * 2048 + cswz1);
        }
    };
    auto ldB = [&](int bsel, int nh, short8 (&bb)[NQ][2]) {
        const char* base = smB + bsel * BSZ + (wc * WN + nh * (WN / 2) + rsel) * 128;
#pragma unroll
        for (int nj = 0; nj < NQ; ++nj) {
            bb[nj][0] = *(const short8*)(base + nj * 2048 + cswz0);
            bb[nj][1] = *(const short8*)(base + nj * 2048 + cswz1);
        }
    };
    auto quad = [&](int MH, int NH, short8 (&aa)[4][2], short8 (&bb)[NQ][2]) {
#pragma unroll
        for (int mi = 0; mi < 4; ++mi)
#pragma unroll
            for (int nj = 0; nj < NQ; ++nj)
#pragma unroll
                for (int kk = 0; kk < 2; ++kk)
                    acc[MH * 4 + mi][NH * NQ + nj] =
                        __builtin_amdgcn_mfma_f32_16x16x32_bf16(
                            aa[mi][kk], bb[nj][kk], acc[MH * 4 + mi][NH * NQ + nj], 0, 0, 0);
    };

    // ---- tap-walk state (init mid-walk for split-K) ----
    const int tap0 = kstart / CPT;
    int c0_ = kstart - tap0 * CPT;
    int dx_ = tap0 % 3;
    long aoff_ = ((long)dx_ + (long)(tap0 / 3) * PADW) * cstride + c0_;
    auto adv = [&]() {
        c0_ += 64; aoff_ += 64;
        if (c0_ == CPT) {
            c0_ = 0; aoff_ += (long)cstride - CPT;
            if (++dx_ == 3) { dx_ = 0; aoff_ += (long)(PADW - 3) * cstride; }
        }
    };

    // ---- prologue: tile0 -> buf0 (8 loads), tile1 -> buf1 (8 loads) ----
    stA(0, 0, aoff_); stA(0, 1, aoff_); stB(0, 0, kstart); stB(0, 1, kstart);
    adv();                                 // aoff_ = state(1)
    stA(1, 0, aoff_); stA(1, 1, aoff_); stB(1, 0, kstart + 64); stB(1, 1, kstart + 64);
    // in-loop, aoff_ holds A-offset of tile kt+1 (advanced at loop end)
    int skb = kstart + 128;

    asm volatile("s_waitcnt vmcnt(8)" ::: "memory");   // tile0 landed
    barrier_();

    for (int kt = 0; kt < KT; ++kt) {
        const int buf = kt & 1;
        // ---- fragment reads: a0 first (q00's only lgkm dep in steady state)
        ldA(buf, 0, a0f);
        if (kt == 0) { ldB(buf, 0, b0); ldB(buf, 1, b1); }   // no pre-read yet
        ldA(buf, 1, a1f);
        // ---- stage A[kt+1] -> buf^1 (kt==0 prologued)
        if (kt >= 1 && kt + 1 < KT) { stA(buf ^ 1, 0, aoff_); stA(buf ^ 1, 1, aoff_); }
        __builtin_amdgcn_s_setprio(1);
        quad(0, 0, a0f, b0);      // b0/b1 pre-read at kt-1; a1 drains underneath
        quad(0, 1, a0f, b1);
        __builtin_amdgcn_s_setprio(0);
        barrier_();               // all waves consumed a0,b0,b1
        // ---- stage B[kt+2] -> buf
        if (kt + 2 < KT) { stB(buf, 0, skb); stB(buf, 1, skb); }
        __builtin_amdgcn_s_setprio(1);
        quad(1, 0, a1f, b0);
        quad(1, 1, a1f, b1);
        __builtin_amdgcn_s_setprio(0);
        if (kt + 2 < KT) {
            // retire A[kt+1] and B[kt+1] staging; leave only B[kt+2]'s 4 loads
            asm volatile("s_waitcnt vmcnt(4)" ::: "memory");
        } else {
            asm volatile("s_waitcnt vmcnt(0)" ::: "memory");
        }
        // ---- PRE-READ next tile's B fragments (B[kt+1] guaranteed landed).
        // Region is rewritten only at (kt+1)'s mid-stage, which every wave
        // reaches after its q00/q01 consumed these values.
        if (kt + 1 < KT) { ldB(buf ^ 1, 0, b0); ldB(buf ^ 1, 1, b1); }
        barrier_();
        adv(); skb += 64;
    }

    // ---- epilogue ----
    const int nl = lane & 15, mq = lane >> 4;
#pragma unroll
    for (int s = 0; s < 8; ++s) {
#pragma unroll
        for (int nj = 0; nj < NSUB; ++nj) {
            int n = n0 + wc * WN + nj * 16 + nl;
            float al = (EPI == 4) ? 1.f : alpha[n];
            float be = (EPI == 4) ? 0.f : beta[n];
#pragma unroll
            for (int r = 0; r < 4; ++r) {
                int m = m0 + wr * 128 + s * 16 + mq * 4 + r;
                float v = acc[s][nj][r] * al + be;
                if (EPI == 0) {
                    int b = m >> 12, h = (m >> 6) & 63, w = m & 63;
                    long addr = ((long)(b * PADW + h + 1) * PADW + (w + 1)) * ostride + ochoff + n;
                    outb[addr] = f2b(v);
                } else if (EPI == 2) {
                    int b = m >> 12, h = (m >> 6) & 63, w = m & 63;
                    outf[((long)(b * nch + n) << 12) + (h * 64 + w)] = v;
                } else {
                    outf[(long)ks * ((long)32768 * nch) + (long)m * nch + n] = v;
                }
            }
        }
    }
}

// ------------------- split-K combine: affine(P0+P1) -> bf16 padded -----------
__global__ void combine_k(const float* __restrict__ P,
                          const float* __restrict__ alpha, const float* __restrict__ beta,
                          u16* __restrict__ dst, int dstride, int choff)
{
    int t = threadIdx.x;
    int m = blockIdx.x * 4 + (t >> 6);
    int n = (t & 63) * 4;
    int b = m >> 12, h = (m >> 6) & 63, w = m & 63;
    f32x4 v0 = *(const f32x4*)&P[(long)m * 256 + n];
    f32x4 v1 = *(const f32x4*)&P[(long)32768 * 256 + (long)m * 256 + n];
    f32x4 al = *(const f32x4*)&alpha[n];
    f32x4 be = *(const f32x4*)&beta[n];
    u16x4 r;
#pragma unroll
    for (int i = 0; i < 4; ++i) r[i] = f2b((v0[i] + v1[i]) * al[i] + be[i]);
    *(u16x4*)&dst[((long)(b * PADW + h + 1) * PADW + (w + 1)) * dstride + choff + n] = r;
}

// ------------------- border zero: CAT (2560ch) + F0 (256ch) -----------------
__global__ void border_k(u16* __restrict__ cat, u16* __restrict__ f0)
{
    int i = blockIdx.x;              // 8 * 260
    int b = i / 260, r = i - b * 260;
    int ph, pw;
    if (r < 66)       { ph = 0;        pw = r; }
    else if (r < 132) { ph = 65;       pw = r - 66; }
    else if (r < 196) { ph = r - 131;  pw = 0; }
    else              { ph = r - 195;  pw = 65; }
    long pix = (long)(b * PADW + ph) * PADW + pw;
    int t = threadIdx.x;
    u16x8 z = {};
    *(u16x8*)&cat[pix * CATC + t * 8] = z;
    if (t < 64) *(u16x8*)&cat[pix * CATC + 2048 + t * 8] = z;
    if (t < 32) *(u16x8*)&f0[pix * 256 + t * 8] = z;
}

// ---------------------------------------------------------------------------
// Small implicit-GEMM conv (128x128, BK=32) — used for qkv / squeeze.
// EPI: 1 = affine -> bf16 flat store, 3 = affine+relu -> mean-reduce.
// ---------------------------------------------------------------------------
template<int TAPS, int EPI>
__global__ __launch_bounds__(256, 2)
void gemm_conv(const u16* __restrict__ A, int cstride, int cpt,
               const u16* __restrict__ Bw, int ktot,
               const float* __restrict__ alpha, const float* __restrict__ beta,
               u16* __restrict__ outb, int ostride, int ochoff,
               float* __restrict__ outf, int n_total)
{
    __shared__ u16 As[128][32];
    __shared__ u16 Bs[128][32];
    __shared__ float red[128];

    const int tid  = threadIdx.x;
    const int lane = tid & 63;
    const int wave = tid >> 6;
    const int wr = wave >> 1, wc = wave & 1;
    const int m0 = blockIdx.y * 128;
    const int n0 = blockIdx.x * 128;

    long pixbase[2];
    long browk[2];
#pragma unroll
    for (int i = 0; i < 2; ++i) {
        int row = i * 64 + (tid >> 2);
        int p = m0 + row;
        int b = p >> 12, h = (p >> 6) & 63, w = p & 63;
        if (TAPS == 1) pixbase[i] = (long)(b * PADW + h + 1) * PADW + (w + 1);
        else           pixbase[i] = (long)(b * PADW + h) * PADW + w;
        browk[i] = (long)(n0 + row) * ktot;
    }
    const int chunk = (tid & 3) * 8;

    f32x4 acc[4][4] = {};

    const int steps = ktot / 32;
    int c0 = 0, dx = 0;
    long toff = 0;
    for (int s = 0; s < steps; ++s) {
        const int k0 = s * 32;
#pragma unroll
        for (int i = 0; i < 2; ++i) {
            const u16* ga = A + (pixbase[i] + ((TAPS == 1) ? 0 : toff)) * cstride + c0 + chunk;
            async_copy16((char*)(&As[0][0]) + i * 4096 + tid * 16, ga);
            const u16* gb = Bw + browk[i] + k0 + chunk;
            async_copy16((char*)(&Bs[0][0]) + i * 4096 + tid * 16, gb);
        }
        asm volatile("s_waitcnt vmcnt(0)" ::: "memory");
        __syncthreads();

        short8 af[4], bf[4];
#pragma unroll
        for (int x = 0; x < 4; ++x) {
            af[x] = *(const short8*)&As[wr * 64 + x * 16 + (lane & 15)][(lane >> 4) * 8];
            bf[x] = *(const short8*)&Bs[wc * 64 + x * 16 + (lane & 15)][(lane >> 4) * 8];
        }
#pragma unroll
        for (int mi = 0; mi < 4; ++mi)
#pragma unroll
            for (int ni = 0; ni < 4; ++ni)
                acc[mi][ni] = __builtin_amdgcn_mfma_f32_16x16x32_bf16(af[mi], bf[ni], acc[mi][ni], 0, 0, 0);
        __syncthreads();

        c0 += 32;
        if (TAPS > 1 && c0 == cpt) {
            c0 = 0; dx++; toff += 1;
            if (dx == 3) { dx = 0; toff += PADW - 3; }
        }
    }

    const int nl = lane & 15;
    const int mq = lane >> 4;

    if (EPI == 3) {
        if (tid < 128) red[tid] = 0.f;
        __syncthreads();
#pragma unroll
        for (int ni = 0; ni < 4; ++ni) {
            int ncol = wc * 64 + ni * 16 + nl;
            int n = n0 + ncol;
            float aa = alpha[n], bb = beta[n];
            float ssum = 0.f;
#pragma unroll
            for (int mi = 0; mi < 4; ++mi)
#pragma unroll
                for (int r = 0; r < 4; ++r)
                    ssum += fmaxf(acc[mi][ni][r] * aa + bb, 0.f);
            atomicAdd(&red[ncol], ssum);
        }
        __syncthreads();
        if (tid < 128) {
            int b = m0 >> 12;
            atomicAdd(&outf[b * 256 + n0 + tid], red[tid]);
        }
    } else {
#pragma unroll
        for (int mi = 0; mi < 4; ++mi) {
#pragma unroll
            for (int r = 0; r < 4; ++r) {
                int m = m0 + wr * 64 + mi * 16 + mq * 4 + r;
#pragma unroll
                for (int ni = 0; ni < 4; ++ni) {
                    int n = n0 + wc * 64 + ni * 16 + nl;
                    float v = acc[mi][ni][r] * alpha[n] + beta[n];
                    outb[(long)m * ostride + n] = f2b(v);
                }
            }
        }
    }
}

// ------------------- x: NCHW f32 -> padded NHWC bf16 (vectorized) -----------
__global__ void xpad_k(const float* __restrict__ x, u16* __restrict__ cat)
{
    __shared__ float T[64][68];
    int bh = blockIdx.y;
    int b = bh >> 6, h = bh & 63;
    int c0 = blockIdx.x * 64;
    int t = threadIdx.x;
    const float* xb = x + (((long)b * 2048 + c0) * 64 + h) * 64;
#pragma unroll
    for (int i = 0; i < 4; ++i) {
        int idx = i * 256 + t;          // c*16 + wq
        int c = idx >> 4, wq = (idx & 15) * 4;
        *(f32x4*)&T[c][wq] = *(const f32x4*)&xb[(long)c * 4096 + wq];
    }
    __syncthreads();
    long pbase = ((long)(b * PADW + h + 1) * PADW + 1) * CATC + c0;
#pragma unroll
    for (int j = 0; j < 2; ++j) {
        int idx = j * 256 + t;          // w*8 + cg
        int w = idx >> 3, cg = (idx & 7) * 8;
        u16x8 r;
#pragma unroll
        for (int u = 0; u < 8; ++u) r[u] = f2b(T[cg + u][w]);
        *(u16x8*)&cat[pbase + (long)w * CATC + cg] = r;
    }
}

// ------------------- weight transforms ---------------------------------------
__global__ void prep_w3(const float* __restrict__ w, u16* __restrict__ o, int O, int C)
{
    int idx = blockIdx.x * 256 + threadIdx.x;
    if (idx >= O * C) return;
    int oo = idx / C, c = idx - oo * C;
    const float* s = w + (long)idx * 9;
    long base = (long)oo * 9 * C + c;
#pragma unroll
    for (int t = 0; t < 9; ++t) o[base + (long)t * C] = f2b(s[t]);
}

__global__ void prep_qkv(const float* __restrict__ qw, const float* __restrict__ kw,
                         const float* __restrict__ vw, u16* __restrict__ o)
{
    int idx = blockIdx.x * 256 + threadIdx.x;   // over 384*256
    int n = idx >> 8, c = idx & 255;
    float v;
    if (n < 32) v = qw[n * 256 + c];
    else if (n < 64) v = kw[(n - 32) * 256 + c];
    else if (n < 320) v = vw[(n - 64) * 256 + c];
    else v = 0.f;
    o[idx] = f2b(v);
}

__global__ void prep_cast(const float* __restrict__ w, u16* __restrict__ o, int n)
{
    int i = blockIdx.x * 256 + threadIdx.x;
    if (i < n) o[i] = f2b(w[i]);
}

__global__ void prep_ab(const float* as, const float* ab, const float* am, const float* av,
                        const float* gs, const float* gb, const float* gm, const float* gv, const float* sqb,
                        const float* bs, const float* bb, const float* bm, const float* bv,
                        const float* ts, const float* tb, const float* tm, const float* tv,
                        const float* qb, const float* kb, const float* vb,
                        float* Aa, float* Ba_, float* Ag, float* Bg, float* Ab2, float* Bb2,
                        float* At, float* Bt, float* Aq, float* Bq)
{
    int i = blockIdx.x * 256 + threadIdx.x;
    if (i < 256) { float al = as[i] * rsqrtf(av[i] + BN_EPS); Aa[i] = al; Ba_[i] = ab[i] - am[i] * al; }
    else if (i < 512) { int n = i - 256; float al = gs[n] * rsqrtf(gv[n] + BN_EPS); Ag[n] = al; Bg[n] = gb[n] - gm[n] * al + sqb[n] * al; }
    else if (i < 768) { int n = i - 512; float al = bs[n] * rsqrtf(bv[n] + BN_EPS); Ab2[n] = al; Bb2[n] = bb[n] - bm[n] * al; }
    else if (i < 1280) { int n = i - 768; float al = ts[n] * rsqrtf(tv[n] + BN_EPS); At[n] = al; Bt[n] = tb[n] - tm[n] * al; }
    else if (i < 1664) { int n = i - 1280; Aq[n] = 1.f; Bq[n] = (n < 32) ? qb[n] : (n < 64) ? kb[n - 32] : (n < 320) ? vb[n - 64] : 0.f; }
}

// ------------------- SE: vec -> gate ----------------------------------------
__global__ void gate_k(const float* __restrict__ vacc, const float* __restrict__ fc1w,
                       const float* __restrict__ fc1b, const float* __restrict__ fc2w,
                       const float* __restrict__ fc2b, float* __restrict__ gate)
{
    __shared__ float v[256], hbuf[128];
    int b = blockIdx.x, t = threadIdx.x;
    v[t] = vacc[b * 256 + t] * (1.f / 4096.f);
    __syncthreads();
    if (t < 128) {
        float s = fc1b[t];
        for (int c = 0; c < 256; ++c) s += v[c] * fc1w[t * 256 + c];
        hbuf[t] = fmaxf(s, 0.f);
    }
    __syncthreads();
    float s = fc2b[t];
    for (int j = 0; j < 128; ++j) s += hbuf[j] * fc2w[t * 128 + j];
    gate[b * 256 + t] = 1.f / (1.f + __expf(-s));
}

// ------------------- out_gap -> cat ch 2304..2560 ----------------------------
__global__ void gap_k(const u16* __restrict__ f0, const float* __restrict__ gate, u16* __restrict__ cat)
{
    int p = blockIdx.x, t = threadIdx.x;
    int b = p >> 12, h = (p >> 6) & 63, w = p & 63;
    long ppad = (long)(b * PADW + h + 1) * PADW + (w + 1);
    float f = b2f(f0[ppad * 256 + t]);
    cat[ppad * CATC + 2304 + t] = f2b(f * gate[b * 256 + t]);
}

// ------------------- CCA: Gram (Q.K^T per column AND per row, one launch) ----
__global__ void gram_k(const u16* __restrict__ qkv, float* eH, float* eW)
{
    __shared__ u16 Qs[64][32];
    __shared__ u16 Ks[64][32];
    int g = blockIdx.x;              // 1024 = 2 modes x 512
    int mode = g >> 9;
    int bx = g & 511;
    int b = bx >> 6, s = bx & 63;
    float* e = mode ? eW : eH;
    int tid = threadIdx.x, lane = tid & 63, wave = tid >> 6;
    {
        int r = tid >> 2, ch = (tid & 3) * 8;
        long pix = (mode == 0) ? ((long)(b * 64 + r) * 64 + s) : ((long)(b * 64 + s) * 64 + r);
        const u16* gp = qkv + pix * 384;
        *(u16x8*)&Qs[r][ch] = *(const u16x8*)(gp + ch);
        *(u16x8*)&Ks[r][ch] = *(const u16x8*)(gp + 32 + ch);
    }
    __syncthreads();
    f32x4 acc[4] = {};
    short8 a = *(const short8*)&Qs[wave * 16 + (lane & 15)][(lane >> 4) * 8];
#pragma unroll
    for (int ni = 0; ni < 4; ++ni) {
        short8 bb = *(const short8*)&Ks[ni * 16 + (lane & 15)][(lane >> 4) * 8];
        acc[ni] = __builtin_amdgcn_mfma_f32_16x16x32_bf16(a, bb, acc[ni], 0, 0, 0);
    }
#pragma unroll
    for (int ni = 0; ni < 4; ++ni)
#pragma unroll
        for (int r = 0; r < 4; ++r) {
            int row = wave * 16 + (lane >> 4) * 4 + r;
            int col = ni * 16 + (lane & 15);
            long pix = (mode == 0) ? ((long)(b * 64 + row) * 64 + s) : ((long)(b * 64 + s) * 64 + row);
            e[pix * 64 + col] = acc[ni][r];
        }
}

// ------------------- CCA: joint softmax over [eH | eW] -----------------------
__global__ void softmax_k(const float* __restrict__ eH, const float* __restrict__ eW,
                          u16* __restrict__ aH, u16* __restrict__ aW)
{
    long row = blockIdx.x * 4 + (threadIdx.x >> 6);
    int lane = threadIdx.x & 63;
    float v0 = eH[row * 64 + lane];
    float v1 = eW[row * 64 + lane];
    float m = fmaxf(v0, v1);
#pragma unroll
    for (int off = 32; off; off >>= 1) m = fmaxf(m, __shfl_xor(m, off));
    float e0 = __expf(v0 - m), e1 = __expf(v1 - m);
    float s = e0 + e1;
#pragma unroll
    for (int off = 32; off; off >>= 1) s += __shfl_xor(s, off);
    float inv = 1.f / s;
    aH[row * 64 + lane] = f2b(e0 * inv);
    aW[row * 64 + lane] = f2b(e1 * inv);
}

// ------------------- CCA: oH = aH . V(column) --------------------------------
__global__ __launch_bounds__(256, 2)
void oh_k(const u16* __restrict__ aH, const u16* __restrict__ qkv, float* __restrict__ oHb)
{
    __shared__ float Al[64][68];
    __shared__ u16 Vl[64][264];
    int bx = blockIdx.x;
    int b = bx >> 6, w = bx & 63;
    int t = threadIdx.x;
#pragma unroll
    for (int pass = 0; pass < 2; ++pass) {
        int r = pass * 32 + (t >> 3);
        int ch = (t & 7) * 8;
        u16x8 v = *(const u16x8*)(aH + ((long)(b * 64 + r) * 64 + w) * 64 + ch);
        f32x4 s0, s1;
#pragma unroll
        for (int u = 0; u < 4; ++u) { s0[u] = b2f(v[u]); s1[u] = b2f(v[4 + u]); }
        *(f32x4*)&Al[r][ch] = s0;
        *(f32x4*)&Al[r][ch + 4] = s1;
    }
#pragma unroll
    for (int pass = 0; pass < 8; ++pass) {
        int i = pass * 8 + (t >> 5);
        int ch = (t & 31) * 8;
        *(u16x8*)&Vl[i][ch] = *(const u16x8*)(qkv + ((long)(b * 64 + i) * 64 + w) * 384 + 64 + ch);
    }
    __syncthreads();
    int hb = (t >> 5) * 8, cb = (t & 31) * 8;
    float acc[8][8] = {};
    for (int i = 0; i < 64; ++i) {
        float av[8], vv[8];
        u16x8 v8 = *(const u16x8*)&Vl[i][cb];
#pragma unroll
        for (int u = 0; u < 8; ++u) av[u] = Al[hb + u][i];
#pragma unroll
        for (int u = 0; u < 8; ++u) vv[u] = b2f(v8[u]);
#pragma unroll
        for (int u = 0; u < 8; ++u)
#pragma unroll
            for (int x = 0; x < 8; ++x)
                acc[u][x] += av[u] * vv[x];
    }
#pragma unroll
    for (int u = 0; u < 8; ++u) {
        long base = ((long)(b * 64 + hb + u) * 64 + w) * 256 + cb;
        f32x4 s0, s1;
#pragma unroll
        for (int x = 0; x < 4; ++x) { s0[x] = acc[u][x]; s1[x] = acc[u][4 + x]; }
        *(f32x4*)&oHb[base] = s0;
        *(f32x4*)&oHb[base + 4] = s1;
    }
}

// ------------------- CCA: oW = aW . V(row); combine -> fout ------------------
__global__ __launch_bounds__(256, 2)
void ow_k(const u16* __restrict__ aW, const u16* __restrict__ qkv, const float* __restrict__ oHb,
          const u16* __restrict__ fin, u16* __restrict__ fout, const float* __restrict__ gamma_p)
{
    __shared__ float Al[64][68];
    __shared__ u16 Vl[64][264];
    int bx = blockIdx.x;
    int b = bx >> 6, h = bx & 63;
    int t = threadIdx.x;
    float gamma = gamma_p[0];
#pragma unroll
    for (int pass = 0; pass < 2; ++pass) {
        int r = pass * 32 + (t >> 3);
        int ch = (t & 7) * 8;
        u16x8 v = *(const u16x8*)(aW + ((long)(b * 64 + h) * 64 + r) * 64 + ch);
        f32x4 s0, s1;
#pragma unroll
        for (int u = 0; u < 4; ++u) { s0[u] = b2f(v[u]); s1[u] = b2f(v[4 + u]); }
        *(f32x4*)&Al[r][ch] = s0;
        *(f32x4*)&Al[r][ch + 4] = s1;
    }
#pragma unroll
    for (int pass = 0; pass < 8; ++pass) {
        int j = pass * 8 + (t >> 5);
        int ch = (t & 31) * 8;
        *(u16x8*)&Vl[j][ch] = *(const u16x8*)(qkv + ((long)(b * 64 + h) * 64 + j) * 384 + 64 + ch);
    }
    __syncthreads();
    int wb = (t >> 5) * 8, cb = (t & 31) * 8;
    float acc[8][8] = {};
    for (int j = 0; j < 64; ++j) {
        float av[8], vv[8];
        u16x8 v8 = *(const u16x8*)&Vl[j][cb];
#pragma unroll
        for (int u = 0; u < 8; ++u) av[u] = Al[wb + u][j];
#pragma unroll
        for (int u = 0; u < 8; ++u) vv[u] = b2f(v8[u]);
#pragma unroll
        for (int u = 0; u < 8; ++u)
#pragma unroll
            for (int x = 0; x < 8; ++x)
                acc[u][x] += av[u] * vv[x];
    }
#pragma unroll
    for (int u = 0; u < 8; ++u) {
        int w = wb + u;
        long pix = ((long)(b * 64 + h) * 64 + w) * 256 + cb;
        long pp = ((long)(b * PADW + h + 1) * PADW + (w + 1)) * 256 + cb;
        u16x8 f8 = *(const u16x8*)&fin[pp];
        f32x4 o0 = *(const f32x4*)&oHb[pix];
        f32x4 o1 = *(const f32x4*)&oHb[pix + 4];
        u16x8 r8;
#pragma unroll
        for (int x = 0; x < 8; ++x) {
            float o = acc[u][x] + ((x < 4) ? o0[x] : o1[x - 4]);
            r8[x] = f2b(gamma * o + b2f(f8[x]));
        }
        *(u16x8*)&fout[pp] = r8;
    }
}

// ---------------------------------------------------------------------------
extern "C" void kernel_launch(void* const* d_in, const int* in_sizes, int n_in,
                              void* d_out, int out_size, void* d_ws, size_t ws_size,
                              hipStream_t stream)
{
    const float* x       = (const float*)d_in[0];
    const float* conva_w = (const float*)d_in[2];
    const float* bn_a_s  = (const float*)d_in[3];
    const float* bn_a_b  = (const float*)d_in[4];
    const float* bn_a_m  = (const float*)d_in[5];
    const float* bn_a_v  = (const float*)d_in[6];
    const float* q_w     = (const float*)d_in[7];
    const float* q_b     = (const float*)d_in[8];
    const float* k_w     = (const float*)d_in[9];
    const float* k_b     = (const float*)d_in[10];
    const float* v_w     = (const float*)d_in[11];
    const float* v_b     = (const float*)d_in[12];
    const float* gamma   = (const float*)d_in[13];
    const float* convb_w = (const float*)d_in[14];
    const float* bn_b_s  = (const float*)d_in[15];
    const float* bn_b_b  = (const float*)d_in[16];
    const float* bn_b_m  = (const float*)d_in[17];
    const float* bn_b_v  = (const float*)d_in[18];
    const float* sq_w    = (const float*)d_in[19];
    const float* sq_b    = (const float*)d_in[20];
    const float* bn_g_s  = (const float*)d_in[21];
    const float* bn_g_b  = (const float*)d_in[22];
    const float* bn_g_m  = (const float*)d_in[23];
    const float* bn_g_v  = (const float*)d_in[24];
    const float* fc1_w   = (const float*)d_in[25];
    const float* fc1_b   = (const float*)d_in[26];
    const float* fc2_w   = (const float*)d_in[27];
    const float* fc2_b   = (const float*)d_in[28];
    const float* bott_w  = (const float*)d_in[29];
    const float* bn_t_s  = (const float*)d_in[30];
    const float* bn_t_b  = (const float*)d_in[31];
    const float* bn_t_m  = (const float*)d_in[32];
    const float* bn_t_v  = (const float*)d_in[33];

    char* ws = (char*)d_ws;
    size_t off = 0;
    auto alloc = [&](size_t bytes) { char* p = ws + off; off += (bytes + 255) & ~(size_t)255; return p; };

    u16*   CAT  = (u16*)  alloc((size_t)8 * PADW * PADW * CATC * 2);
    u16*   F0   = (u16*)  alloc((size_t)8 * PADW * PADW * 256 * 2);
    u16*   F1   = (u16*)  alloc((size_t)8 * PADW * PADW * 256 * 2);
    size_t cca_off = off;                 // CCA scratch block — time-shared with P
    u16*   QKV  = (u16*)  alloc((size_t)32768 * 384 * 2);
    float* EH   = (float*)alloc((size_t)32768 * 64 * 4);
    float* EWb  = (float*)alloc((size_t)32768 * 64 * 4);
    u16*   AH   = (u16*)  alloc((size_t)32768 * 64 * 2);
    u16*   AW   = (u16*)  alloc((size_t)32768 * 64 * 2);
    float* OHB  = (float*)alloc((size_t)32768 * 256 * 4);
    float* P    = (float*)(ws + cca_off); // 67.2MB split-K partials (aliases QKV..OHB = 84MB)
    u16*   WA   = (u16*)  alloc((size_t)256 * 18432 * 2);
    u16*   WB   = (u16*)  alloc((size_t)256 * 2304 * 2);
    u16*   WT   = (u16*)  alloc((size_t)512 * 23040 * 2);
    u16*   WQKV = (u16*)  alloc((size_t)384 * 256 * 2);
    u16*   WSQ  = (u16*)  alloc((size_t)256 * 256 * 2);
    float* Aa   = (float*)alloc(256 * 4);
    float* Ba_  = (float*)alloc(256 * 4);
    float* Ag   = (float*)alloc(256 * 4);
    float* Bg   = (float*)alloc(256 * 4);
    float* Ab2  = (float*)alloc(256 * 4);
    float* Bb2  = (float*)alloc(256 * 4);
    float* At   = (float*)alloc(512 * 4);
    float* Bt   = (float*)alloc(512 * 4);
    float* Aq   = (float*)alloc(384 * 4);
    float* Bq   = (float*)alloc(384 * 4);
    float* VACC = (float*)alloc(8 * 256 * 4);
    float* GATE = (float*)alloc(8 * 256 * 4);

    hipFuncSetAttribute((const void*)gemm8<9, 256, 4, 2048, 1, 2>,
                        hipFuncAttributeMaxDynamicSharedMemorySize, 131072);
    hipFuncSetAttribute((const void*)gemm8<9, 256, 4, 256, 1, 2>,
                        hipFuncAttributeMaxDynamicSharedMemorySize, 131072);
    hipFuncSetAttribute((const void*)gemm8<9, 256, 2, 2560, 2, 1>,
                        hipFuncAttributeMaxDynamicSharedMemorySize, 131072);

    hipMemsetAsync(VACC, 0, 8 * 256 * 4, stream);

    border_k<<<8 * 260, 256, 0, stream>>>(CAT, F0);
    prep_w3<<<(256 * 2048 + 255) / 256, 256, 0, stream>>>(conva_w, WA, 256, 2048);
    prep_w3<<<(256 * 256 + 255) / 256, 256, 0, stream>>>(convb_w, WB, 256, 256);
    prep_w3<<<(512 * 2560 + 255) / 256, 256, 0, stream>>>(bott_w, WT, 512, 2560);
    prep_qkv<<<384, 256, 0, stream>>>(q_w, k_w, v_w, WQKV);
    prep_cast<<<256, 256, 0, stream>>>(sq_w, WSQ, 65536);
    prep_ab<<<7, 256, 0, stream>>>(bn_a_s, bn_a_b, bn_a_m, bn_a_v,
                                   bn_g_s, bn_g_b, bn_g_m, bn_g_v, sq_b,
                                   bn_b_s, bn_b_b, bn_b_m, bn_b_v,
                                   bn_t_s, bn_t_b, bn_t_m, bn_t_v,
                                   q_b, k_b, v_b,
                                   Aa, Ba_, Ag, Bg, Ab2, Bb2, At, Bt, Aq, Bq);
    xpad_k<<<dim3(32, 512), 256, 0, stream>>>(x, CAT);

    // conv_a + bn_a -> F0  (split-K=2 -> f32 partials -> combine)
    gemm8<9, 256, 4, 2048, 1, 2><<<256, 512, 131072, stream>>>(
        CAT, CATC, WA, 18432, 9216, Aa, Ba_, nullptr, 0, 0, P, 256);
    combine_k<<<8192, 256, 0, stream>>>(P, Aa, Ba_, F0, 256, 0);

    // squeeze conv + bn_g + relu + mean -> VACC
    gemm_conv<1, 3><<<dim3(2, 256), 256, 0, stream>>>(F0, 256, 256, WSQ, 256, Ag, Bg, nullptr, 0, 0, VACC, 0);
    gate_k<<<8, 256, 0, stream>>>(VACC, fc1_w, fc1_b, fc2_w, fc2_b, GATE);
    gap_k<<<32768, 256, 0, stream>>>(F0, GATE, CAT);

    // 2 recurrences of criss-cross attention (P region free only after this)
    for (int rec = 0; rec < 2; ++rec) {
        u16* fin = rec ? F1 : F0;
        u16* fout = rec ? F0 : F1;
        gemm_conv<1, 1><<<dim3(3, 256), 256, 0, stream>>>(fin, 256, 256, WQKV, 256, Aq, Bq, QKV, 384, 0, nullptr, 0);
        gram_k<<<1024, 256, 0, stream>>>(QKV, EH, EWb);
        softmax_k<<<8192, 256, 0, stream>>>(EH, EWb, AH, AW);
        oh_k<<<512, 256, 0, stream>>>(AH, QKV, OHB);
        ow_k<<<512, 256, 0, stream>>>(AW, QKV, OHB, fin, fout, gamma);
    }

    // conv_b + bn_b -> CAT channels [2048, 2304)  (split-K=2)
    gemm8<9, 256, 4, 256, 1, 2><<<256, 512, 131072, stream>>>(
        F0, 256, WB, 2304, 1152, Ab2, Bb2, nullptr, 0, 0, P, 256);
    combine_k<<<8192, 256, 0, stream>>>(P, Ab2, Bb2, CAT, CATC, 2048);

    // bottleneck conv + bn_t -> d_out  (BN=256: 128 x 2 tiles)
    gemm8<9, 256, 2, 2560, 2, 1><<<256, 512, 131072, stream>>>(
        CAT, CATC, WT, 23040, 23040, At, Bt, nullptr, 0, 0, (float*)d_out, 512);
}